// Round 3
// baseline (334.271 us; speedup 1.0000x reference)
//
#include <hip/hip_runtime.h>
#include <hip/hip_bf16.h>

#define T_TOK 4096
#define DDIM  768
#define IDIM  2048
#define NEXP  8
#define LSTR  40   // gemm1 LDS row stride in bf16 (80 B): 20-bank rotation, ~2-way (free)
#define LSTR2 72   // gemm2 LDS row stride in bf16 (144 B): 4-bank rotation, ~2-way

typedef __attribute__((ext_vector_type(8))) short  bfrag;   // 8 bf16 = 4 VGPR
typedef __attribute__((ext_vector_type(4))) float  ffrag;   // 4 f32 acc

static __device__ __forceinline__ unsigned short f2bf(float f) {
    union { float f; unsigned u; } v; v.f = f;
    unsigned r = v.u + 0x7FFFu + ((v.u >> 16) & 1u);   // RNE
    return (unsigned short)(r >> 16);
}

// packed RNE f32x2 -> bf16x2 via v_cvt_pk_bf16_f32 (1 instr, same RNE rounding)
static __device__ __forceinline__ unsigned cvt2(float x, float y) {
    union { __hip_bfloat162 h; unsigned u; } v;
    v.h = __float22bfloat162_rn(make_float2(x, y));
    return v.u;
}

static __device__ __forceinline__ uint4 cvt8(float4 a, float4 b) {
    uint4 o;
    o.x = cvt2(a.x, a.y); o.y = cvt2(a.z, a.w);
    o.z = cvt2(b.x, b.y); o.w = cvt2(b.z, b.w);
    return o;
}

// Barrier that does NOT drain vmcnt: prefetched global loads stay in flight.
// lgkmcnt(0) seals this wave's ds ops; barrier => all waves' writes visible.
#define PIPE_BAR() do { \
    asm volatile("s_waitcnt lgkmcnt(0)" ::: "memory"); \
    __builtin_amdgcn_s_barrier(); \
    __builtin_amdgcn_sched_barrier(0); \
} while (0)

// ws int layout: counts[8] @0, offsets[9] @16
__global__ void k_sort(const int* __restrict__ pos, int* __restrict__ ws_i,
                       int* __restrict__ perm) {
    __shared__ int hist[NEXP], cursor[NEXP];
    const int tid = threadIdx.x;
    if (tid < NEXP) hist[tid] = 0;
    __syncthreads();
    for (int i = tid; i < T_TOK; i += 1024)
        atomicAdd(&hist[pos[i]], 1);
    __syncthreads();
    if (tid == 0) {
        int s = 0;
        for (int e = 0; e < NEXP; ++e) {
            cursor[e] = s;
            ws_i[e] = hist[e];
            ws_i[16 + e] = s;
            s += hist[e];
        }
        ws_i[16 + NEXP] = s;
    }
    __syncthreads();
    for (int i = tid; i < T_TOK; i += 1024) {
        int p = atomicAdd(&cursor[pos[i]], 1);
        perm[p] = i;
    }
}

// GEMM1 (gather fused): x[perm] fp32 -> bf16 @ gate/up^T -> h = silu(g)*u, bf16
// BM=128, BN=64 (x2 matrices), BK=32; LDS double-buffer, single-set reg prefetch,
// one non-draining barrier per K-step.
__launch_bounds__(256, 4)
__global__ void k_gemm1(const float* __restrict__ x,
                        const int* __restrict__ perm,
                        const float* __restrict__ gate_w,
                        const float* __restrict__ up_w,
                        unsigned short* __restrict__ hg,
                        const int* __restrict__ ws_i) {
    const int e   = blockIdx.z;
    const int cnt = ws_i[e];
    const int m0  = blockIdx.y * 128;
    if (m0 >= cnt) return;
    const int off = ws_i[16 + e];
    const int n0  = blockIdx.x * 64;

    const int tid  = threadIdx.x;
    const int lane = tid & 63;
    const int wave = tid >> 6;
    const int wm   = wave & 1;
    const int wn   = wave >> 1;

    __shared__ __align__(16) unsigned short lsA[2][128 * LSTR];  // 20 KB
    __shared__ __align__(16) unsigned short lsG[2][64 * LSTR];   // 10 KB
    __shared__ __align__(16) unsigned short lsU[2][64 * LSTR];   // 10 KB

    const float* gate_e = gate_w + (size_t)e * (IDIM * DDIM);
    const float* up_e   = up_w   + (size_t)e * (IDIM * DDIM);

    // staging maps: A 128 rows x 32 cols fp32 (gathered), 16 floats/thread
    const int arow = tid >> 1, aq = tid & 1;     // row 0..127, col-half 0/1
    const int brow = tid >> 2, bq = tid & 3;     // row 0..63,  col-oct  0..3

    int trow = off + m0 + arow; if (trow > T_TOK - 1) trow = T_TOK - 1;
    const int tok = perm[trow];
    const float* ap = x + (size_t)tok * DDIM + aq * 16;
    const float* gp = gate_e + (size_t)(n0 + brow) * DDIM + bq * 8;
    const float* up = up_e   + (size_t)(n0 + brow) * DDIM + bq * 8;

    ffrag accG[4][2], accU[4][2];
    const ffrag fz = {0.f, 0.f, 0.f, 0.f};
    for (int mi = 0; mi < 4; ++mi)
        for (int ni = 0; ni < 2; ++ni) { accG[mi][ni] = fz; accU[mi][ni] = fz; }

    const int koff = (lane >> 4) * 8;
    const int rsel = lane & 15;

    // single prefetch set: 8 float4 = 32 VGPR
    float4 Pa0, Pa1, Pa2, Pa3, Pg0, Pg1, Pu0, Pu1;

#define G1_LOAD(kb) do { \
    Pa0 = *reinterpret_cast<const float4*>(ap + (kb)); \
    Pa1 = *reinterpret_cast<const float4*>(ap + (kb) + 4); \
    Pa2 = *reinterpret_cast<const float4*>(ap + (kb) + 8); \
    Pa3 = *reinterpret_cast<const float4*>(ap + (kb) + 12); \
    Pg0 = *reinterpret_cast<const float4*>(gp + (kb)); \
    Pg1 = *reinterpret_cast<const float4*>(gp + (kb) + 4); \
    Pu0 = *reinterpret_cast<const float4*>(up + (kb)); \
    Pu1 = *reinterpret_cast<const float4*>(up + (kb) + 4); } while (0)

#define G1_STORE(B) do { \
    *reinterpret_cast<uint4*>(&lsA[B][arow * LSTR + aq * 16])     = cvt8(Pa0, Pa1); \
    *reinterpret_cast<uint4*>(&lsA[B][arow * LSTR + aq * 16 + 8]) = cvt8(Pa2, Pa3); \
    *reinterpret_cast<uint4*>(&lsG[B][brow * LSTR + bq * 8]) = cvt8(Pg0, Pg1); \
    *reinterpret_cast<uint4*>(&lsU[B][brow * LSTR + bq * 8]) = cvt8(Pu0, Pu1); } while (0)

#define G1_COMPUTE(B) do { \
    bfrag a[4], bg[2], bu[2]; \
    _Pragma("unroll") \
    for (int mi = 0; mi < 4; ++mi) \
        a[mi] = *reinterpret_cast<const bfrag*>(&lsA[B][(wm * 64 + mi * 16 + rsel) * LSTR + koff]); \
    _Pragma("unroll") \
    for (int ni = 0; ni < 2; ++ni) { \
        bg[ni] = *reinterpret_cast<const bfrag*>(&lsG[B][(wn * 32 + ni * 16 + rsel) * LSTR + koff]); \
        bu[ni] = *reinterpret_cast<const bfrag*>(&lsU[B][(wn * 32 + ni * 16 + rsel) * LSTR + koff]); \
    } \
    _Pragma("unroll") \
    for (int mi = 0; mi < 4; ++mi) { \
        _Pragma("unroll") \
        for (int ni = 0; ni < 2; ++ni) { \
            accG[mi][ni] = __builtin_amdgcn_mfma_f32_16x16x32_bf16(a[mi], bg[ni], accG[mi][ni], 0, 0, 0); \
            accU[mi][ni] = __builtin_amdgcn_mfma_f32_16x16x32_bf16(a[mi], bu[ni], accU[mi][ni], 0, 0, 0); \
        } \
    } } while (0)

    // prologue: tile0 -> lds[0]; tile1 loads in flight across barrier
    G1_LOAD(0);
    G1_STORE(0);
    G1_LOAD(32);
    PIPE_BAR();

    #pragma unroll 2
    for (int kt = 0; kt < 24; ++kt) {
        const int cur = kt & 1;
        if (kt < 23) G1_STORE(cur ^ 1);        // waits vmcnt via reg dep (tile kt+1)
        if (kt < 22) G1_LOAD((kt + 2) * 32);   // issue; flies across barrier
        G1_COMPUTE(cur);
        PIPE_BAR();
    }
#undef G1_LOAD
#undef G1_STORE
#undef G1_COMPUTE

    // epilogue: h = silu(g)*u; C layout col=lane&15, row=(lane>>4)*4+r
    const int colb  = lane & 15;
    const int rquad = (lane >> 4) * 4;
    #pragma unroll
    for (int mi = 0; mi < 4; ++mi)
        #pragma unroll
        for (int ni = 0; ni < 2; ++ni) {
            int n = n0 + wn * 32 + ni * 16 + colb;
            #pragma unroll
            for (int r = 0; r < 4; ++r) {
                int ml = wm * 64 + mi * 16 + rquad + r;
                if (m0 + ml < cnt) {
                    float g = accG[mi][ni][r];
                    float u = accU[mi][ni][r];
                    float h = (g / (1.0f + __expf(-g))) * u;
                    hg[(size_t)(off + m0 + ml) * IDIM + n] = f2bf(h);
                }
            }
        }
}

// GEMM2: hg[cnt x 2048] bf16 @ down^T, full K (no split-K, no atomics),
// BM=64, BN=64, BK=64; same pipeline; direct permuted store.
__launch_bounds__(256, 4)
__global__ void k_gemm2(const unsigned short* __restrict__ hg,
                        const float* __restrict__ down_w,
                        float* __restrict__ out,
                        const int* __restrict__ ws_i,
                        const int* __restrict__ perm) {
    const int e   = blockIdx.z;
    const int cnt = ws_i[e];
    const int m0  = blockIdx.y * 64;
    if (m0 >= cnt) return;
    const int off = ws_i[16 + e];
    const int n0  = blockIdx.x * 64;

    const int tid  = threadIdx.x;
    const int lane = tid & 63;
    const int wave = tid >> 6;
    const int wm   = wave & 1;
    const int wn   = wave >> 1;

    __shared__ __align__(16) unsigned short lsA[2][64 * LSTR2];  // 18 KB
    __shared__ __align__(16) unsigned short lsB[2][64 * LSTR2];  // 18 KB

    const float* down_e = down_w + (size_t)e * (DDIM * IDIM);

    // staging maps: 64 rows x 64 cols per tile, 16 elems/thread
    const int arow = tid >> 2, aq = tid & 3;

    int g0 = off + m0 + arow; if (g0 > T_TOK - 1) g0 = T_TOK - 1;
    const unsigned short* ap = hg + (size_t)g0 * IDIM + aq * 16;
    const float* bp = down_e + (size_t)(n0 + arow) * IDIM + aq * 16;

    ffrag acc[2][2];
    const ffrag fz = {0.f, 0.f, 0.f, 0.f};
    for (int mi = 0; mi < 2; ++mi)
        for (int ni = 0; ni < 2; ++ni) acc[mi][ni] = fz;

    const int koff = (lane >> 4) * 8;
    const int rsel = lane & 15;

    uint4  Pa0, Pa1;              // 16 bf16
    float4 Pb0, Pb1, Pb2, Pb3;    // 16 fp32

#define G2_LOAD(kb) do { \
    Pa0 = *reinterpret_cast<const uint4*>(ap + (kb)); \
    Pa1 = *reinterpret_cast<const uint4*>(ap + (kb) + 8); \
    Pb0 = *reinterpret_cast<const float4*>(bp + (kb)); \
    Pb1 = *reinterpret_cast<const float4*>(bp + (kb) + 4); \
    Pb2 = *reinterpret_cast<const float4*>(bp + (kb) + 8); \
    Pb3 = *reinterpret_cast<const float4*>(bp + (kb) + 12); } while (0)

#define G2_STORE(B) do { \
    *reinterpret_cast<uint4*>(&lsA[B][arow * LSTR2 + aq * 16])     = Pa0; \
    *reinterpret_cast<uint4*>(&lsA[B][arow * LSTR2 + aq * 16 + 8]) = Pa1; \
    *reinterpret_cast<uint4*>(&lsB[B][arow * LSTR2 + aq * 16])     = cvt8(Pb0, Pb1); \
    *reinterpret_cast<uint4*>(&lsB[B][arow * LSTR2 + aq * 16 + 8]) = cvt8(Pb2, Pb3); } while (0)

#define G2_COMPUTE(B) do { \
    _Pragma("unroll") \
    for (int h = 0; h < 2; ++h) { \
        const int ko = h * 32 + koff; \
        bfrag a[2], b[2]; \
        _Pragma("unroll") \
        for (int mi = 0; mi < 2; ++mi) \
            a[mi] = *reinterpret_cast<const bfrag*>(&lsA[B][(wm * 32 + mi * 16 + rsel) * LSTR2 + ko]); \
        _Pragma("unroll") \
        for (int ni = 0; ni < 2; ++ni) \
            b[ni] = *reinterpret_cast<const bfrag*>(&lsB[B][(wn * 32 + ni * 16 + rsel) * LSTR2 + ko]); \
        _Pragma("unroll") \
        for (int mi = 0; mi < 2; ++mi) { \
            _Pragma("unroll") \
            for (int ni = 0; ni < 2; ++ni) \
                acc[mi][ni] = __builtin_amdgcn_mfma_f32_16x16x32_bf16(a[mi], b[ni], acc[mi][ni], 0, 0, 0); \
        } \
    } } while (0)

    G2_LOAD(0);
    G2_STORE(0);
    G2_LOAD(64);
    PIPE_BAR();

    #pragma unroll 2
    for (int kt = 0; kt < 32; ++kt) {
        const int cur = kt & 1;
        if (kt < 31) G2_STORE(cur ^ 1);
        if (kt < 30) G2_LOAD((kt + 2) * 64);
        G2_COMPUTE(cur);
        PIPE_BAR();
    }
#undef G2_LOAD
#undef G2_STORE
#undef G2_COMPUTE

    // epilogue: direct permuted store (each (tok, n) written exactly once)
    const int colb  = lane & 15;
    const int rquad = (lane >> 4) * 4;
    #pragma unroll
    for (int mi = 0; mi < 2; ++mi)
        #pragma unroll
        for (int ni = 0; ni < 2; ++ni) {
            int n = n0 + wn * 32 + ni * 16 + colb;
            #pragma unroll
            for (int r = 0; r < 4; ++r) {
                int ml = wm * 32 + mi * 16 + rquad + r;
                if (m0 + ml < cnt) {
                    int tok = perm[off + m0 + ml];
                    out[(size_t)tok * DDIM + n] = acc[mi][ni][r];
                }
            }
        }
}

extern "C" void kernel_launch(void* const* d_in, const int* in_sizes, int n_in,
                              void* d_out, int out_size, void* d_ws, size_t ws_size,
                              hipStream_t stream) {
    const float* x      = (const float*)d_in[0];
    const int*   pos    = (const int*)d_in[1];
    const float* gate_w = (const float*)d_in[3];
    const float* up_w   = (const float*)d_in[4];
    const float* down_w = (const float*)d_in[5];
    float* out = (float*)d_out;

    char* ws = (char*)d_ws;
    int* ws_i = (int*)ws;
    int* perm = (int*)(ws + 1024);
    unsigned short* hg = (unsigned short*)(ws + 32768);   // 16.8 MB bf16

    k_sort<<<dim3(1), dim3(1024), 0, stream>>>(pos, ws_i, perm);

    dim3 g1(IDIM / 64, T_TOK / 128, NEXP);
    k_gemm1<<<g1, dim3(256), 0, stream>>>(x, perm, gate_w, up_w, hg, ws_i);
    dim3 g2(DDIM / 64, T_TOK / 64, NEXP);
    k_gemm2<<<g2, dim3(256), 0, stream>>>(hg, down_w, out, ws_i, perm);
}

// Round 4
// 285.765 us; speedup vs baseline: 1.1697x; 1.1697x over previous
//
#include <hip/hip_runtime.h>
#include <hip/hip_bf16.h>

#define T_TOK 4096
#define DDIM  768
#define IDIM  2048
#define NEXP  8
#define LSTR  40   // gemm1 LDS row stride in bf16 (80 B): 20-bank rotation, ~2-way (free)
#define LSTR2 72   // gemm2 LDS row stride in bf16 (144 B): 4-bank rotation, ~2-way

typedef __attribute__((ext_vector_type(8))) short  bfrag;   // 8 bf16 = 4 VGPR
typedef __attribute__((ext_vector_type(4))) float  ffrag;   // 4 f32 acc

static __device__ __forceinline__ unsigned short f2bf(float f) {
    union { float f; unsigned u; } v; v.f = f;
    unsigned r = v.u + 0x7FFFu + ((v.u >> 16) & 1u);   // RNE
    return (unsigned short)(r >> 16);
}

// packed RNE f32x2 -> bf16x2 via v_cvt_pk_bf16_f32 (1 instr, same RNE rounding)
static __device__ __forceinline__ unsigned cvt2(float x, float y) {
    union { __hip_bfloat162 h; unsigned u; } v;
    v.h = __float22bfloat162_rn(make_float2(x, y));
    return v.u;
}

static __device__ __forceinline__ uint4 cvt8(float4 a, float4 b) {
    uint4 o;
    o.x = cvt2(a.x, a.y); o.y = cvt2(a.z, a.w);
    o.z = cvt2(b.x, b.y); o.w = cvt2(b.z, b.w);
    return o;
}

// Barrier that does NOT drain vmcnt: prefetched global loads stay in flight.
// lgkmcnt(0) seals this wave's ds ops; barrier => all waves' writes visible.
#define PIPE_BAR() do { \
    asm volatile("s_waitcnt lgkmcnt(0)" ::: "memory"); \
    __builtin_amdgcn_s_barrier(); \
    __builtin_amdgcn_sched_barrier(0); \
} while (0)

// ws int layout: counts[8] @0, offsets[9] @16
__global__ void k_sort(const int* __restrict__ pos, int* __restrict__ ws_i,
                       int* __restrict__ perm) {
    __shared__ int hist[NEXP], cursor[NEXP];
    const int tid = threadIdx.x;
    if (tid < NEXP) hist[tid] = 0;
    __syncthreads();
    for (int i = tid; i < T_TOK; i += 1024)
        atomicAdd(&hist[pos[i]], 1);
    __syncthreads();
    if (tid == 0) {
        int s = 0;
        for (int e = 0; e < NEXP; ++e) {
            cursor[e] = s;
            ws_i[e] = hist[e];
            ws_i[16 + e] = s;
            s += hist[e];
        }
        ws_i[16 + NEXP] = s;
    }
    __syncthreads();
    for (int i = tid; i < T_TOK; i += 1024) {
        int p = atomicAdd(&cursor[pos[i]], 1);
        perm[p] = i;
    }
}

// GEMM1 (gather fused): x[perm] fp32 -> bf16 @ gate/up^T -> h = silu(g)*u, bf16
// BM=128, BN=64 (x2 matrices), BK=32; LDS double-buffer, single-set reg prefetch,
// one non-draining barrier per K-step.
// launch_bounds (256,3): reg cap 170 > natural 136 (64 acc + ~72 arch) -> no spill,
// 3 blocks/CU. (256,4) capped at 128 and spilled the prefetch set (round-3 lesson).
__launch_bounds__(256, 3)
__global__ void k_gemm1(const float* __restrict__ x,
                        const int* __restrict__ perm,
                        const float* __restrict__ gate_w,
                        const float* __restrict__ up_w,
                        unsigned short* __restrict__ hg,
                        const int* __restrict__ ws_i) {
    const int e   = blockIdx.z;
    const int cnt = ws_i[e];
    const int m0  = blockIdx.y * 128;
    if (m0 >= cnt) return;
    const int off = ws_i[16 + e];
    const int n0  = blockIdx.x * 64;

    const int tid  = threadIdx.x;
    const int lane = tid & 63;
    const int wave = tid >> 6;
    const int wm   = wave & 1;
    const int wn   = wave >> 1;

    __shared__ __align__(16) unsigned short lsA[2][128 * LSTR];  // 20 KB
    __shared__ __align__(16) unsigned short lsG[2][64 * LSTR];   // 10 KB
    __shared__ __align__(16) unsigned short lsU[2][64 * LSTR];   // 10 KB

    const float* gate_e = gate_w + (size_t)e * (IDIM * DDIM);
    const float* up_e   = up_w   + (size_t)e * (IDIM * DDIM);

    // staging maps: A 128 rows x 32 cols fp32 (gathered), 16 floats/thread
    const int arow = tid >> 1, aq = tid & 1;     // row 0..127, col-half 0/1
    const int brow = tid >> 2, bq = tid & 3;     // row 0..63,  col-oct  0..3

    int trow = off + m0 + arow; if (trow > T_TOK - 1) trow = T_TOK - 1;
    const int tok = perm[trow];
    const float* ap = x + (size_t)tok * DDIM + aq * 16;
    const float* gp = gate_e + (size_t)(n0 + brow) * DDIM + bq * 8;
    const float* up = up_e   + (size_t)(n0 + brow) * DDIM + bq * 8;

    ffrag accG[4][2], accU[4][2];
    const ffrag fz = {0.f, 0.f, 0.f, 0.f};
    for (int mi = 0; mi < 4; ++mi)
        for (int ni = 0; ni < 2; ++ni) { accG[mi][ni] = fz; accU[mi][ni] = fz; }

    const int koff = (lane >> 4) * 8;
    const int rsel = lane & 15;

    // single prefetch set: 8 float4 = 32 VGPR
    float4 Pa0, Pa1, Pa2, Pa3, Pg0, Pg1, Pu0, Pu1;

#define G1_LOAD(kb) do { \
    Pa0 = *reinterpret_cast<const float4*>(ap + (kb)); \
    Pa1 = *reinterpret_cast<const float4*>(ap + (kb) + 4); \
    Pa2 = *reinterpret_cast<const float4*>(ap + (kb) + 8); \
    Pa3 = *reinterpret_cast<const float4*>(ap + (kb) + 12); \
    Pg0 = *reinterpret_cast<const float4*>(gp + (kb)); \
    Pg1 = *reinterpret_cast<const float4*>(gp + (kb) + 4); \
    Pu0 = *reinterpret_cast<const float4*>(up + (kb)); \
    Pu1 = *reinterpret_cast<const float4*>(up + (kb) + 4); } while (0)

#define G1_STORE(B) do { \
    *reinterpret_cast<uint4*>(&lsA[B][arow * LSTR + aq * 16])     = cvt8(Pa0, Pa1); \
    *reinterpret_cast<uint4*>(&lsA[B][arow * LSTR + aq * 16 + 8]) = cvt8(Pa2, Pa3); \
    *reinterpret_cast<uint4*>(&lsG[B][brow * LSTR + bq * 8]) = cvt8(Pg0, Pg1); \
    *reinterpret_cast<uint4*>(&lsU[B][brow * LSTR + bq * 8]) = cvt8(Pu0, Pu1); } while (0)

#define G1_COMPUTE(B) do { \
    bfrag a[4], bg[2], bu[2]; \
    _Pragma("unroll") \
    for (int mi = 0; mi < 4; ++mi) \
        a[mi] = *reinterpret_cast<const bfrag*>(&lsA[B][(wm * 64 + mi * 16 + rsel) * LSTR + koff]); \
    _Pragma("unroll") \
    for (int ni = 0; ni < 2; ++ni) { \
        bg[ni] = *reinterpret_cast<const bfrag*>(&lsG[B][(wn * 32 + ni * 16 + rsel) * LSTR + koff]); \
        bu[ni] = *reinterpret_cast<const bfrag*>(&lsU[B][(wn * 32 + ni * 16 + rsel) * LSTR + koff]); \
    } \
    _Pragma("unroll") \
    for (int mi = 0; mi < 4; ++mi) { \
        _Pragma("unroll") \
        for (int ni = 0; ni < 2; ++ni) { \
            accG[mi][ni] = __builtin_amdgcn_mfma_f32_16x16x32_bf16(a[mi], bg[ni], accG[mi][ni], 0, 0, 0); \
            accU[mi][ni] = __builtin_amdgcn_mfma_f32_16x16x32_bf16(a[mi], bu[ni], accU[mi][ni], 0, 0, 0); \
        } \
    } } while (0)

    // prologue: tile0 -> lds[0]; tile1 loads in flight across barrier
    G1_LOAD(0);
    G1_STORE(0);
    G1_LOAD(32);
    PIPE_BAR();

    #pragma unroll 2
    for (int kt = 0; kt < 24; ++kt) {
        const int cur = kt & 1;
        if (kt < 23) G1_STORE(cur ^ 1);        // waits vmcnt via reg dep (tile kt+1)
        if (kt < 22) G1_LOAD((kt + 2) * 32);   // issue; flies across barrier
        G1_COMPUTE(cur);
        PIPE_BAR();
    }
#undef G1_LOAD
#undef G1_STORE
#undef G1_COMPUTE

    // epilogue: h = silu(g)*u; C layout col=lane&15, row=(lane>>4)*4+r
    const int colb  = lane & 15;
    const int rquad = (lane >> 4) * 4;
    #pragma unroll
    for (int mi = 0; mi < 4; ++mi)
        #pragma unroll
        for (int ni = 0; ni < 2; ++ni) {
            int n = n0 + wn * 32 + ni * 16 + colb;
            #pragma unroll
            for (int r = 0; r < 4; ++r) {
                int ml = wm * 64 + mi * 16 + rquad + r;
                if (m0 + ml < cnt) {
                    float g = accG[mi][ni][r];
                    float u = accU[mi][ni][r];
                    float h = (g / (1.0f + __expf(-g))) * u;
                    hg[(size_t)(off + m0 + ml) * IDIM + n] = f2bf(h);
                }
            }
        }
}

// GEMM2: hg[cnt x 2048] bf16 @ down^T, full K (no split-K, no atomics),
// BM=64, BN=64, BK=64; same pipeline; direct permuted store.
__launch_bounds__(256, 4)
__global__ void k_gemm2(const unsigned short* __restrict__ hg,
                        const float* __restrict__ down_w,
                        float* __restrict__ out,
                        const int* __restrict__ ws_i,
                        const int* __restrict__ perm) {
    const int e   = blockIdx.z;
    const int cnt = ws_i[e];
    const int m0  = blockIdx.y * 64;
    if (m0 >= cnt) return;
    const int off = ws_i[16 + e];
    const int n0  = blockIdx.x * 64;

    const int tid  = threadIdx.x;
    const int lane = tid & 63;
    const int wave = tid >> 6;
    const int wm   = wave & 1;
    const int wn   = wave >> 1;

    __shared__ __align__(16) unsigned short lsA[2][64 * LSTR2];  // 18 KB
    __shared__ __align__(16) unsigned short lsB[2][64 * LSTR2];  // 18 KB

    const float* down_e = down_w + (size_t)e * (DDIM * IDIM);

    // staging maps: 64 rows x 64 cols per tile, 16 elems/thread
    const int arow = tid >> 2, aq = tid & 3;

    int g0 = off + m0 + arow; if (g0 > T_TOK - 1) g0 = T_TOK - 1;
    const unsigned short* ap = hg + (size_t)g0 * IDIM + aq * 16;
    const float* bp = down_e + (size_t)(n0 + arow) * IDIM + aq * 16;

    ffrag acc[2][2];
    const ffrag fz = {0.f, 0.f, 0.f, 0.f};
    for (int mi = 0; mi < 2; ++mi)
        for (int ni = 0; ni < 2; ++ni) acc[mi][ni] = fz;

    const int koff = (lane >> 4) * 8;
    const int rsel = lane & 15;

    uint4  Pa0, Pa1;              // 16 bf16
    float4 Pb0, Pb1, Pb2, Pb3;    // 16 fp32

#define G2_LOAD(kb) do { \
    Pa0 = *reinterpret_cast<const uint4*>(ap + (kb)); \
    Pa1 = *reinterpret_cast<const uint4*>(ap + (kb) + 8); \
    Pb0 = *reinterpret_cast<const float4*>(bp + (kb)); \
    Pb1 = *reinterpret_cast<const float4*>(bp + (kb) + 4); \
    Pb2 = *reinterpret_cast<const float4*>(bp + (kb) + 8); \
    Pb3 = *reinterpret_cast<const float4*>(bp + (kb) + 12); } while (0)

#define G2_STORE(B) do { \
    *reinterpret_cast<uint4*>(&lsA[B][arow * LSTR2 + aq * 16])     = Pa0; \
    *reinterpret_cast<uint4*>(&lsA[B][arow * LSTR2 + aq * 16 + 8]) = Pa1; \
    *reinterpret_cast<uint4*>(&lsB[B][arow * LSTR2 + aq * 16])     = cvt8(Pb0, Pb1); \
    *reinterpret_cast<uint4*>(&lsB[B][arow * LSTR2 + aq * 16 + 8]) = cvt8(Pb2, Pb3); } while (0)

#define G2_COMPUTE(B) do { \
    _Pragma("unroll") \
    for (int h = 0; h < 2; ++h) { \
        const int ko = h * 32 + koff; \
        bfrag a[2], b[2]; \
        _Pragma("unroll") \
        for (int mi = 0; mi < 2; ++mi) \
            a[mi] = *reinterpret_cast<const bfrag*>(&lsA[B][(wm * 32 + mi * 16 + rsel) * LSTR2 + ko]); \
        _Pragma("unroll") \
        for (int ni = 0; ni < 2; ++ni) \
            b[ni] = *reinterpret_cast<const bfrag*>(&lsB[B][(wn * 32 + ni * 16 + rsel) * LSTR2 + ko]); \
        _Pragma("unroll") \
        for (int mi = 0; mi < 2; ++mi) { \
            _Pragma("unroll") \
            for (int ni = 0; ni < 2; ++ni) \
                acc[mi][ni] = __builtin_amdgcn_mfma_f32_16x16x32_bf16(a[mi], b[ni], acc[mi][ni], 0, 0, 0); \
        } \
    } } while (0)

    G2_LOAD(0);
    G2_STORE(0);
    G2_LOAD(64);
    PIPE_BAR();

    #pragma unroll 2
    for (int kt = 0; kt < 32; ++kt) {
        const int cur = kt & 1;
        if (kt < 31) G2_STORE(cur ^ 1);
        if (kt < 30) G2_LOAD((kt + 2) * 64);
        G2_COMPUTE(cur);
        PIPE_BAR();
    }
#undef G2_LOAD
#undef G2_STORE
#undef G2_COMPUTE

    // epilogue: direct permuted store (each (tok, n) written exactly once)
    const int colb  = lane & 15;
    const int rquad = (lane >> 4) * 4;
    #pragma unroll
    for (int mi = 0; mi < 2; ++mi)
        #pragma unroll
        for (int ni = 0; ni < 2; ++ni) {
            int n = n0 + wn * 32 + ni * 16 + colb;
            #pragma unroll
            for (int r = 0; r < 4; ++r) {
                int ml = wm * 32 + mi * 16 + rquad + r;
                if (m0 + ml < cnt) {
                    int tok = perm[off + m0 + ml];
                    out[(size_t)tok * DDIM + n] = acc[mi][ni][r];
                }
            }
        }
}

extern "C" void kernel_launch(void* const* d_in, const int* in_sizes, int n_in,
                              void* d_out, int out_size, void* d_ws, size_t ws_size,
                              hipStream_t stream) {
    const float* x      = (const float*)d_in[0];
    const int*   pos    = (const int*)d_in[1];
    const float* gate_w = (const float*)d_in[3];
    const float* up_w   = (const float*)d_in[4];
    const float* down_w = (const float*)d_in[5];
    float* out = (float*)d_out;

    char* ws = (char*)d_ws;
    int* ws_i = (int*)ws;
    int* perm = (int*)(ws + 1024);
    unsigned short* hg = (unsigned short*)(ws + 32768);   // 16.8 MB bf16

    k_sort<<<dim3(1), dim3(1024), 0, stream>>>(pos, ws_i, perm);

    dim3 g1(IDIM / 64, T_TOK / 128, NEXP);
    k_gemm1<<<g1, dim3(256), 0, stream>>>(x, perm, gate_w, up_w, hg, ws_i);
    dim3 g2(DDIM / 64, T_TOK / 64, NEXP);
    k_gemm2<<<g2, dim3(256), 0, stream>>>(hg, down_w, out, ws_i, perm);
}